// Round 8
// baseline (179.908 us; speedup 1.0000x reference)
//
#include <hip/hip_runtime.h>

#define BATCH 4
#define CH    256
#define DQ    32
#define NPIX  4096
#define LOG2E 1.44269504088896340736f

typedef unsigned short u16;
typedef unsigned int   u32;
typedef __attribute__((ext_vector_type(8))) short short8;
typedef __attribute__((ext_vector_type(16))) float f32x16;

// W pre-converted to A-frag-swizzled split-bf16: [jt][hi/lo][kk][half][j][e8]
__device__ __align__(16) u16 g_wbf[10 * 2 * 8192];
__device__ float g_bias[10 * 32];

__device__ __forceinline__ float b2f(u32 u) {
  union { u32 i; float f; } v; v.i = (u & 0xffffu) << 16; return v.f;
}
__device__ __forceinline__ u16 f2b(float f) {            // RNE fp32->bf16
  union { float f; u32 i; } v; v.f = f;
  u32 x = v.i; x += 0x7fffu + ((x >> 16) & 1u);
  return (u16)(x >> 16);
}
__device__ __forceinline__ float fexp2(float x) {
#if __has_builtin(__builtin_amdgcn_exp2f)
  return __builtin_amdgcn_exp2f(x);
#else
  return __expf(x * 0.69314718055994530942f);
#endif
}
// packed RNE fp32x2 -> bf16x2 (low = a, high = b); T12 recipe (no builtin)
__device__ __forceinline__ u32 cvtpk_bf16(float a, float b) {
  u32 r;
  asm("v_cvt_pk_bf16_f32 %0, %1, %2" : "=v"(r) : "v"(a), "v"(b));
  return r;
}

// C->B-operand half-wave exchange for the P tile (HW-verified r1-r7: pass).
__device__ __forceinline__ void half_swap(u32 a0, u32 a1, u32 b0, u32 b1,
                                          int hl, uint4& o) {
#if __has_builtin(__builtin_amdgcn_permlane32_swap)
  const auto r0 = __builtin_amdgcn_permlane32_swap((int)a0, (int)b0, false, false);
  const auto r1 = __builtin_amdgcn_permlane32_swap((int)a1, (int)b1, false, false);
  o.x = (u32)r0[0]; o.y = (u32)r1[0]; o.z = (u32)r0[1]; o.w = (u32)r1[1];
#else
  const u32 s0 = hl ? a0 : b0;
  const u32 s1 = hl ? a1 : b1;
  const u32 r0 = (u32)__shfl_xor((int)s0, 32);
  const u32 r1 = (u32)__shfl_xor((int)s1, 32);
  o.x = hl ? r0 : a0; o.y = hl ? r1 : a1;
  o.z = hl ? b0 : r0; o.w = hl ? b1 : r1;
#endif
}

// ---------------------------------------------------------------------------
// xprep (+fused wprep on the z==BATCH slice) — unchanged from r2.
// ---------------------------------------------------------------------------
__global__ __launch_bounds__(256) void xprep(
    const float* __restrict__ x, u16* __restrict__ xt_hi, u16* __restrict__ xt_lo,
    const float* __restrict__ Wq, const float* __restrict__ bq,
    const float* __restrict__ Wk, const float* __restrict__ bk,
    const float* __restrict__ Wv, const float* __restrict__ bv)
{
  const int t = threadIdx.x;

  if (blockIdx.z == BATCH) {                   // ---- wprep role ----
    if (blockIdx.y != 0 || blockIdx.x >= 10) return;
    const int jt = blockIdx.x;
    const float* Wsrc; const float* bsrc; int jrow0; float scale = 1.f;
    if (jt == 0)      { Wsrc = Wq; bsrc = bq; jrow0 = 0; scale = LOG2E; }
    else if (jt == 1) { Wsrc = Wk; bsrc = bk; jrow0 = 0; }
    else              { Wsrc = Wv; bsrc = bv; jrow0 = (jt - 2) * 32; }
    u16* wdst = g_wbf + (size_t)jt * 16384;
    for (int i = 0; i < 32; ++i) {
      const int flat = i * 256 + t;
      const int j = flat >> 8, e = flat & 255;
      const float v = Wsrc[(size_t)(jrow0 + j) * CH + e] * scale;
      const u16 hi = f2b(v);
      const u16 lo = f2b(v - b2f(hi));
      const int idx = (((e >> 4) * 2 + ((e >> 3) & 1)) * 32 + j) * 8 + (e & 7);
      wdst[idx] = hi; wdst[8192 + idx] = lo;
    }
    if (t < 32) g_bias[jt * 32 + t] = bsrc[jrow0 + t] * scale;
    return;
  }

  // ---- xprep role ----
  const int nt = blockIdx.x, kb4 = blockIdx.y * 4, b = blockIdx.z;
  const int n0 = nt * 128, c0 = blockIdx.y * 64;
  __shared__ u32 xls[64][129];                 // [c local][n local], hi | lo<<16

  const int tn = t & 127, cp = t >> 7;
  for (int i = 0; i < 32; ++i) {
    const int c = cp + 2 * i;
    const float v = x[((size_t)b * CH + c0 + c) * NPIX + n0 + tn];
    const u16 h = f2b(v);
    const u16 l = f2b(v - b2f(h));
    xls[c][tn] = (u32)h | ((u32)l << 16);
  }
  __syncthreads();

  for (int rep = 0; rep < 4; ++rep) {
    const int id = t + 256 * rep;              // 0..1023
    const int kkhl = id >> 7, n = id & 127;    // kkhl = (kk4*2 + hl)
    union { short8 s; uint4 u; } vh, vl;
    #pragma unroll
    for (int j = 0; j < 8; ++j) {
      const u32 p = xls[kkhl * 8 + j][n];
      vh.s[j] = (short)(p & 0xffffu);
      vl.s[j] = (short)(p >> 16);
    }
    const size_t o = ((((size_t)(b * 32 + nt) * 16 + kb4 + (kkhl >> 1)) * 2
                       + (kkhl & 1)) * 128 + n) * 8;
    *(uint4*)(xt_hi + o) = vh.u;
    *(uint4*)(xt_lo + o) = vl.u;
  }
}

// ---------------------------------------------------------------------------
// proj — unchanged from r2 (barrier-free, LDS-free, XCD-affine).
// ---------------------------------------------------------------------------
__global__ __launch_bounds__(256, 4) void proj(
    const u16* __restrict__ xt_hi, const u16* __restrict__ xt_lo,
    u16* __restrict__ q_t, u16* __restrict__ k_t, u16* __restrict__ v_swz)
{
  const int L = blockIdx.x;
  const int xcd = L & 7, s = L >> 3;           // s in [0,160)
  const int jt = s >> 4;                       // 0..9
  const int pair = xcd * 16 + (s & 15);        // 0..127 (nt,b)
  const int nt = pair >> 2, b = pair & 3;

  const int t = threadIdx.x;
  const int w = t >> 6, lane = t & 63, hl = lane >> 5, l31 = lane & 31;
  const int nb = w * 32 + l31, n = nt * 128 + nb;

  const u16* __restrict__ wb = g_wbf + (size_t)jt * 16384;
  const size_t xtile = (size_t)(b * 32 + nt) * 16 * 2 * 128 * 8;
  const u16* __restrict__ xh = xt_hi + xtile;
  const u16* __restrict__ xl = xt_lo + xtile;

  f32x16 acc1, acc2;
  #pragma unroll
  for (int r = 0; r < 16; ++r) { acc1[r] = 0.f; acc2[r] = 0.f; }

  #pragma unroll
  for (int kk = 0; kk < 16; ++kk) {
    const int aoff = ((kk * 2 + hl) * 32 + l31) * 8;
    const short8 wah = *(const short8*)(wb + aoff);
    const short8 wal = *(const short8*)(wb + 8192 + aoff);
    const int boff = ((kk * 2 + hl) * 128 + nb) * 8;
    const short8 xbh = *(const short8*)(xh + boff);
    const short8 xbl = *(const short8*)(xl + boff);
    acc1 = __builtin_amdgcn_mfma_f32_32x32x16_bf16(wah, xbh, acc1, 0, 0, 0);
    acc2 = __builtin_amdgcn_mfma_f32_32x32x16_bf16(wah, xbl, acc2, 0, 0, 0);
    acc2 = __builtin_amdgcn_mfma_f32_32x32x16_bf16(wal, xbh, acc2, 0, 0, 0);
  }

  f32x16 accv;
  #pragma unroll
  for (int r = 0; r < 16; ++r)
    accv[r] = acc1[r] + acc2[r]
            + g_bias[jt * 32 + (r & 3) + 8 * (r >> 2) + 4 * hl];

  if (jt <= 1) {                               // q_t / k_t: [n][d], 4x b64 stores
    u16* dst = (jt == 0) ? q_t : k_t;
    #pragma unroll
    for (int r2 = 0; r2 < 4; ++r2) {
      uint2 pk;
      pk.x = (u32)f2b(accv[4 * r2 + 0]) | ((u32)f2b(accv[4 * r2 + 1]) << 16);
      pk.y = (u32)f2b(accv[4 * r2 + 2]) | ((u32)f2b(accv[4 * r2 + 3]) << 16);
      *(uint2*)(dst + ((size_t)b * NPIX + n) * DQ + 4 * hl + 8 * r2) = pk;
    }
  } else {                                     // v_swz scatter
    const int mc = nt * 4 + w;
    const int kc = (l31 >> 4) & 1, h3 = (l31 >> 3) & 1, j8 = l31 & 7;
    u16* dst = v_swz + (((((size_t)b * 128 + mc) * 8 + (jt - 2)) * 2 + kc) * 2 + h3) * 256 + j8;
    #pragma unroll
    for (int r = 0; r < 16; ++r) {
      const int c5 = (r & 3) + 8 * (r >> 2) + 4 * hl;
      dst[c5 * 8] = f2b(accv[r]);
    }
  }
}

// ---------------------------------------------------------------------------
// attn v7: r7 (verified, 62.0us) + two register-budget-aware edits.
// Budget: acc 128 AGPR + 116 VGPR = 244/wave; 2-wave boundary at 256 ->
// 12 regs headroom.  (1) K-prefetch depth-2 (+8 VGPR -> ~252): S(cc+1)
// was waiting ~300cy on its own K-load (adjacent issue->use); now K(mc+2)
// loads at iter top into named rotating regs (no dynamic index, rule #20),
// giving ~2000cy distance.  (2) Parallel epilogue: one extra combine round
// puts the full sum in cbuf, then all 4 waves store (was: wave 0 serial).
// No pragmas / asm waits / setprio (r1/r5 lessons).
// grid (512, XCD-affine), 256 thr.
// ---------------------------------------------------------------------------
__global__ __launch_bounds__(256, 2) void attn(
    const u16* __restrict__ q_t, const u16* __restrict__ k_t,
    const u16* __restrict__ v_swz, const float* __restrict__ x,
    const float* __restrict__ gamma, float* __restrict__ out)
{
  const int L = blockIdx.x;
  const int xcd = L & 7, slot = L >> 3;        // slot 0..63
  const int b = xcd >> 1;                      // XCD pair {2b,2b+1} <- batch b
  const int nt = slot * 2 + (xcd & 1);         // 0..127, bijective
  const int n0 = nt * 32;

  const int t = threadIdx.x;
  const int w = t >> 6, lane = t & 63, hl = lane >> 5, l31 = lane & 31;

  __shared__ float cbuf[8192];                 // 32 KB combine buffer
  __shared__ float lbuf[4][64];

  // Q B-frags (persistent): B[k=d][col=n=l31]
  short8 qf[2];
  #pragma unroll
  for (int kd = 0; kd < 2; ++kd)
    qf[kd] = *(const short8*)(q_t + ((size_t)b * NPIX + n0 + l31) * DQ + kd * 16 + hl * 8);

  f32x16 acc[8];
  #pragma unroll
  for (int ct = 0; ct < 8; ++ct)
    #pragma unroll
    for (int r = 0; r < 16; ++r) acc[ct][r] = 0.f;
  float lrun = 0.f;

  const u16* __restrict__ kb = k_t + (size_t)b * NPIX * DQ;

  // ---- prologue: st = S(0); kfc = K(1) (for S(1) in iter 0) ----
  f32x16 st;
  short8 kfc0, kfc1;
  {
    const int mc0 = w * 32;
    const short8 k00 = *(const short8*)(kb + (mc0 * 32 + l31) * DQ + hl * 8);
    const short8 k01 = *(const short8*)(kb + (mc0 * 32 + l31) * DQ + 16 + hl * 8);
    #pragma unroll
    for (int r = 0; r < 16; ++r) st[r] = 0.f;
    st = __builtin_amdgcn_mfma_f32_32x32x16_bf16(k00, qf[0], st, 0, 0, 0);
    st = __builtin_amdgcn_mfma_f32_32x32x16_bf16(k01, qf[1], st, 0, 0, 0);
    kfc0 = *(const short8*)(kb + ((mc0 + 1) * 32 + l31) * DQ + hl * 8);
    kfc1 = *(const short8*)(kb + ((mc0 + 1) * 32 + l31) * DQ + 16 + hl * 8);
  }

  for (int cc = 0; cc < 32; ++cc) {
    const int mc = w * 32 + cc;

    // ---- prefetch K(mc+2) into rotation regs (used NEXT iter's S) ----
    const int mcp = w * 32 + ((cc < 30) ? cc + 2 : 31);
    const short8 kfn0 = *(const short8*)(kb + (mcp * 32 + l31) * DQ + hl * 8);
    const short8 kfn1 = *(const short8*)(kb + (mcp * 32 + l31) * DQ + 16 + hl * 8);

    // ---- P(cc) = exp2(st) (q pre-scaled by log2e), l partial, pack ----
    u32 pk[4][2];
    #pragma unroll
    for (int g = 0; g < 4; ++g) {
      const float e0 = fexp2(st[4 * g + 0]);
      const float e1 = fexp2(st[4 * g + 1]);
      const float e2 = fexp2(st[4 * g + 2]);
      const float e3 = fexp2(st[4 * g + 3]);
      lrun += (e0 + e1) + (e2 + e3);
      pk[g][0] = cvtpk_bf16(e0, e1);
      pk[g][1] = cvtpk_bf16(e2, e3);
    }

    // ---- st = S(cc+1) with PREFETCHED kfc (loaded last iter, ~2000cy
    //      ago); result not consumed until next iter's exp ----
    #pragma unroll
    for (int r = 0; r < 16; ++r) st[r] = 0.f;
    st = __builtin_amdgcn_mfma_f32_32x32x16_bf16(kfc0, qf[0], st, 0, 0, 0);
    st = __builtin_amdgcn_mfma_f32_32x32x16_bf16(kfc1, qf[1], st, 0, 0, 0);

    // ---- PV(cc): acc[ct] += V^T(A) . P^T(B) per kc ----
    const size_t vbase = ((size_t)b * 128 + mc) * 8192;
    #pragma unroll
    for (int kc = 0; kc < 2; ++kc) {
      union { uint4 u; short8 s; } bu;
      half_swap(pk[2 * kc][0], pk[2 * kc][1], pk[2 * kc + 1][0], pk[2 * kc + 1][1], hl, bu.u);
      #pragma unroll
      for (int ct = 0; ct < 8; ++ct) {
        const short8 av = *(const short8*)(v_swz + vbase + (size_t)(((ct * 2 + kc) * 2 + hl) * 256) + l31 * 8);
        acc[ct] = __builtin_amdgcn_mfma_f32_32x32x16_bf16(av, bu.s, acc[ct], 0, 0, 0);
      }
    }

    // ---- rotate K prefetch regs (renamed away by unroller) ----
    kfc0 = kfn0; kfc1 = kfn1;
  }

  // ---- cross-wave additive combine: 4 serialized rounds into cbuf ----
  lbuf[w][lane] = lrun;
  __syncthreads();
  for (int src = 0; src < 4; ++src) {
    if (w == src) {
      #pragma unroll
      for (int ct = 0; ct < 8; ++ct)
        #pragma unroll
        for (int r = 0; r < 16; ++r) {
          const int idx = (ct * 16 + r) * 64 + lane;
          if (src == 0) cbuf[idx] = acc[ct][r];
          else          cbuf[idx] += acc[ct][r];
        }
    }
    __syncthreads();
  }

  // ---- parallel epilogue: all 4 waves; 256 thr cover 32 col x 256 ch ----
  const int col = t & 31, chg = t >> 5;        // chg 0..7, 32 ch each
  float l = 0.f;
  #pragma unroll
  for (int gg = 0; gg < 4; ++gg)
    l += lbuf[gg][col] + lbuf[gg][col + 32];
  const float linv = 1.0f / l;
  const float gmv = gamma[0];
  #pragma unroll
  for (int i = 0; i < 32; ++i) {
    const int ch = chg * 32 + i;
    const int ct = ch >> 5, c5 = ch & 31;
    const int hl2 = (c5 >> 2) & 1, rl = c5 & 3, rh = c5 >> 3;
    const float cb = cbuf[(ct * 16 + rh * 4 + rl) * 64 + hl2 * 32 + col];
    const size_t oidx = ((size_t)b * CH + ch) * NPIX + n0 + col;
    out[oidx] = gmv * cb * linv + x[oidx];
  }
}

// ---------------------------------------------------------------------------
extern "C" void kernel_launch(void* const* d_in, const int* in_sizes, int n_in,
                              void* d_out, int out_size, void* d_ws, size_t ws_size,
                              hipStream_t stream) {
  const float* x  = (const float*)d_in[0];
  const float* Wq = (const float*)d_in[1];
  const float* bq = (const float*)d_in[2];
  const float* Wk = (const float*)d_in[3];
  const float* bk = (const float*)d_in[4];
  const float* Wv = (const float*)d_in[5];
  const float* bv = (const float*)d_in[6];
  const float* gm = (const float*)d_in[7];
  float* out = (float*)d_out;

  // ws: q_t 1MB | k_t 1MB | v_swz 8MB (all bf16) — 10MB
  const size_t qk_elems = (size_t)BATCH * NPIX * DQ;
  const size_t v_elems  = (size_t)BATCH * NPIX * CH;
  const size_t need = (2 * qk_elems + v_elems) * sizeof(u16);
  if (ws_size < need) return;

  u16* q_t   = (u16*)d_ws;
  u16* k_t   = q_t + qk_elems;
  u16* v_swz = k_t + qk_elems;

  // xt planes live in d_out (dead until attn's epilogue overwrites it)
  u16* xt_hi = (u16*)d_out;
  u16* xt_lo = xt_hi + (size_t)BATCH * NPIX * CH;

  xprep<<<dim3(NPIX / 128, CH / 64, BATCH + 1), 256, 0, stream>>>(
      x, xt_hi, xt_lo, Wq, bq, Wk, bk, Wv, bv);
  proj<<<dim3(32 * 10 * BATCH), 256, 0, stream>>>(xt_hi, xt_lo, q_t, k_t, v_swz);
  attn<<<dim3((NPIX / 32) * BATCH), 256, 0, stream>>>(q_t, k_t, v_swz, x, gm, out);
}

// Round 11
// 156.908 us; speedup vs baseline: 1.1466x; 1.1466x over previous
//
#include <hip/hip_runtime.h>

#define BATCH 4
#define CH    256
#define DQ    32
#define NPIX  4096
#define LOG2E 1.44269504088896340736f

typedef unsigned short u16;
typedef unsigned int   u32;
typedef __attribute__((ext_vector_type(8))) short short8;
typedef __attribute__((ext_vector_type(16))) float f32x16;

// W pre-converted to A-frag-swizzled split-bf16: [jt][hi/lo][kk][half][j][e8]
__device__ __align__(16) u16 g_wbf[10 * 2 * 8192];
__device__ float g_bias[10 * 32];

__device__ __forceinline__ float b2f(u32 u) {
  union { u32 i; float f; } v; v.i = (u & 0xffffu) << 16; return v.f;
}
__device__ __forceinline__ u16 f2b(float f) {            // RNE fp32->bf16
  union { float f; u32 i; } v; v.f = f;
  u32 x = v.i; x += 0x7fffu + ((x >> 16) & 1u);
  return (u16)(x >> 16);
}
__device__ __forceinline__ float fexp2(float x) {
#if __has_builtin(__builtin_amdgcn_exp2f)
  return __builtin_amdgcn_exp2f(x);
#else
  return __expf(x * 0.69314718055994530942f);
#endif
}
// packed RNE fp32x2 -> bf16x2 (low = a, high = b); T12 recipe (no builtin)
__device__ __forceinline__ u32 cvtpk_bf16(float a, float b) {
  u32 r;
  asm("v_cvt_pk_bf16_f32 %0, %1, %2" : "=v"(r) : "v"(a), "v"(b));
  return r;
}

// C->B-operand half-wave exchange for the P tile (HW-verified r1-r8: pass).
__device__ __forceinline__ void half_swap(u32 a0, u32 a1, u32 b0, u32 b1,
                                          int hl, uint4& o) {
#if __has_builtin(__builtin_amdgcn_permlane32_swap)
  const auto r0 = __builtin_amdgcn_permlane32_swap((int)a0, (int)b0, false, false);
  const auto r1 = __builtin_amdgcn_permlane32_swap((int)a1, (int)b1, false, false);
  o.x = (u32)r0[0]; o.y = (u32)r1[0]; o.z = (u32)r0[1]; o.w = (u32)r1[1];
#else
  const u32 s0 = hl ? a0 : b0;
  const u32 s1 = hl ? a1 : b1;
  const u32 r0 = (u32)__shfl_xor((int)s0, 32);
  const u32 r1 = (u32)__shfl_xor((int)s1, 32);
  o.x = hl ? r0 : a0; o.y = hl ? r1 : a1;
  o.z = hl ? b0 : r0; o.w = hl ? b1 : r1;
#endif
}

// ---------------------------------------------------------------------------
// xprep (+fused wprep on the z==BATCH slice) — unchanged from r2.
// ---------------------------------------------------------------------------
__global__ __launch_bounds__(256) void xprep(
    const float* __restrict__ x, u16* __restrict__ xt_hi, u16* __restrict__ xt_lo,
    const float* __restrict__ Wq, const float* __restrict__ bq,
    const float* __restrict__ Wk, const float* __restrict__ bk,
    const float* __restrict__ Wv, const float* __restrict__ bv)
{
  const int t = threadIdx.x;

  if (blockIdx.z == BATCH) {                   // ---- wprep role ----
    if (blockIdx.y != 0 || blockIdx.x >= 10) return;
    const int jt = blockIdx.x;
    const float* Wsrc; const float* bsrc; int jrow0; float scale = 1.f;
    if (jt == 0)      { Wsrc = Wq; bsrc = bq; jrow0 = 0; scale = LOG2E; }
    else if (jt == 1) { Wsrc = Wk; bsrc = bk; jrow0 = 0; }
    else              { Wsrc = Wv; bsrc = bv; jrow0 = (jt - 2) * 32; }
    u16* wdst = g_wbf + (size_t)jt * 16384;
    for (int i = 0; i < 32; ++i) {
      const int flat = i * 256 + t;
      const int j = flat >> 8, e = flat & 255;
      const float v = Wsrc[(size_t)(jrow0 + j) * CH + e] * scale;
      const u16 hi = f2b(v);
      const u16 lo = f2b(v - b2f(hi));
      const int idx = (((e >> 4) * 2 + ((e >> 3) & 1)) * 32 + j) * 8 + (e & 7);
      wdst[idx] = hi; wdst[8192 + idx] = lo;
    }
    if (t < 32) g_bias[jt * 32 + t] = bsrc[jrow0 + t] * scale;
    return;
  }

  // ---- xprep role ----
  const int nt = blockIdx.x, kb4 = blockIdx.y * 4, b = blockIdx.z;
  const int n0 = nt * 128, c0 = blockIdx.y * 64;
  __shared__ u32 xls[64][129];                 // [c local][n local], hi | lo<<16

  const int tn = t & 127, cp = t >> 7;
  for (int i = 0; i < 32; ++i) {
    const int c = cp + 2 * i;
    const float v = x[((size_t)b * CH + c0 + c) * NPIX + n0 + tn];
    const u16 h = f2b(v);
    const u16 l = f2b(v - b2f(h));
    xls[c][tn] = (u32)h | ((u32)l << 16);
  }
  __syncthreads();

  for (int rep = 0; rep < 4; ++rep) {
    const int id = t + 256 * rep;              // 0..1023
    const int kkhl = id >> 7, n = id & 127;    // kkhl = (kk4*2 + hl)
    union { short8 s; uint4 u; } vh, vl;
    #pragma unroll
    for (int j = 0; j < 8; ++j) {
      const u32 p = xls[kkhl * 8 + j][n];
      vh.s[j] = (short)(p & 0xffffu);
      vl.s[j] = (short)(p >> 16);
    }
    const size_t o = ((((size_t)(b * 32 + nt) * 16 + kb4 + (kkhl >> 1)) * 2
                       + (kkhl & 1)) * 128 + n) * 8;
    *(uint4*)(xt_hi + o) = vh.u;
    *(uint4*)(xt_lo + o) = vl.u;
  }
}

// ---------------------------------------------------------------------------
// proj — unchanged from r2 (barrier-free, LDS-free, XCD-affine).
// ---------------------------------------------------------------------------
__global__ __launch_bounds__(256, 4) void proj(
    const u16* __restrict__ xt_hi, const u16* __restrict__ xt_lo,
    u16* __restrict__ q_t, u16* __restrict__ k_t, u16* __restrict__ v_swz)
{
  const int L = blockIdx.x;
  const int xcd = L & 7, s = L >> 3;           // s in [0,160)
  const int jt = s >> 4;                       // 0..9
  const int pair = xcd * 16 + (s & 15);        // 0..127 (nt,b)
  const int nt = pair >> 2, b = pair & 3;

  const int t = threadIdx.x;
  const int w = t >> 6, lane = t & 63, hl = lane >> 5, l31 = lane & 31;
  const int nb = w * 32 + l31, n = nt * 128 + nb;

  const u16* __restrict__ wb = g_wbf + (size_t)jt * 16384;
  const size_t xtile = (size_t)(b * 32 + nt) * 16 * 2 * 128 * 8;
  const u16* __restrict__ xh = xt_hi + xtile;
  const u16* __restrict__ xl = xt_lo + xtile;

  f32x16 acc1, acc2;
  #pragma unroll
  for (int r = 0; r < 16; ++r) { acc1[r] = 0.f; acc2[r] = 0.f; }

  #pragma unroll
  for (int kk = 0; kk < 16; ++kk) {
    const int aoff = ((kk * 2 + hl) * 32 + l31) * 8;
    const short8 wah = *(const short8*)(wb + aoff);
    const short8 wal = *(const short8*)(wb + 8192 + aoff);
    const int boff = ((kk * 2 + hl) * 128 + nb) * 8;
    const short8 xbh = *(const short8*)(xh + boff);
    const short8 xbl = *(const short8*)(xl + boff);
    acc1 = __builtin_amdgcn_mfma_f32_32x32x16_bf16(wah, xbh, acc1, 0, 0, 0);
    acc2 = __builtin_amdgcn_mfma_f32_32x32x16_bf16(wah, xbl, acc2, 0, 0, 0);
    acc2 = __builtin_amdgcn_mfma_f32_32x32x16_bf16(wal, xbh, acc2, 0, 0, 0);
  }

  f32x16 accv;
  #pragma unroll
  for (int r = 0; r < 16; ++r)
    accv[r] = acc1[r] + acc2[r]
            + g_bias[jt * 32 + (r & 3) + 8 * (r >> 2) + 4 * hl];

  if (jt <= 1) {                               // q_t / k_t: [n][d], 4x b64 stores
    u16* dst = (jt == 0) ? q_t : k_t;
    #pragma unroll
    for (int r2 = 0; r2 < 4; ++r2) {
      uint2 pk;
      pk.x = (u32)f2b(accv[4 * r2 + 0]) | ((u32)f2b(accv[4 * r2 + 1]) << 16);
      pk.y = (u32)f2b(accv[4 * r2 + 2]) | ((u32)f2b(accv[4 * r2 + 3]) << 16);
      *(uint2*)(dst + ((size_t)b * NPIX + n) * DQ + 4 * hl + 8 * r2) = pk;
    }
  } else {                                     // v_swz scatter
    const int mc = nt * 4 + w;
    const int kc = (l31 >> 4) & 1, h3 = (l31 >> 3) & 1, j8 = l31 & 7;
    u16* dst = v_swz + (((((size_t)b * 128 + mc) * 8 + (jt - 2)) * 2 + kc) * 2 + h3) * 256 + j8;
    #pragma unroll
    for (int r = 0; r < 16; ++r) {
      const int c5 = (r & 3) + 8 * (r >> 2) + 4 * hl;
      dst[c5 * 8] = f2b(accv[r]);
    }
  }
}

// ---------------------------------------------------------------------------
// attn — r7 verbatim (session-best VERIFIED: total 157.2us, attn 62.0us,
// absmax 0.082).  r2 structure + S-pipeline reorder: exp/pack consumes LAST
// iter's st first (freeing st), then S(cc+1) into the same st regs (K-load
// + S-MFMA latency hides under PV + iter boundary), then PV(cc).
// Compiler-scheduled throughout — r1/r5/r8 each showed manual pipelining
// (unroll pins, asm waits, K-rotation regs) displaces the compiler's V-load
// hoisting: free VGPRs during PV ARE the V-prefetch depth (r8: -16 regs =
// +21us).  r9's combine/epilogue variant failed correctness inexplicably
// (its pieces passed in r8/r7); this is the fully-verified version.
// grid (512, XCD-affine: batch -> XCD pair), 256 thr.
// ---------------------------------------------------------------------------
__global__ __launch_bounds__(256, 2) void attn(
    const u16* __restrict__ q_t, const u16* __restrict__ k_t,
    const u16* __restrict__ v_swz, const float* __restrict__ x,
    const float* __restrict__ gamma, float* __restrict__ out)
{
  const int L = blockIdx.x;
  const int xcd = L & 7, slot = L >> 3;        // slot 0..63
  const int b = xcd >> 1;                      // XCD pair {2b,2b+1} <- batch b
  const int nt = slot * 2 + (xcd & 1);         // 0..127, bijective
  const int n0 = nt * 32;

  const int t = threadIdx.x;
  const int w = t >> 6, lane = t & 63, hl = lane >> 5, l31 = lane & 31;

  __shared__ float cbuf[8192];                 // 32 KB combine buffer
  __shared__ float lbuf[4][64];

  // Q B-frags (persistent): B[k=d][col=n=l31]
  short8 qf[2];
  #pragma unroll
  for (int kd = 0; kd < 2; ++kd)
    qf[kd] = *(const short8*)(q_t + ((size_t)b * NPIX + n0 + l31) * DQ + kd * 16 + hl * 8);

  f32x16 acc[8];
  #pragma unroll
  for (int ct = 0; ct < 8; ++ct)
    #pragma unroll
    for (int r = 0; r < 16; ++r) acc[ct][r] = 0.f;
  float lrun = 0.f;

  const u16* __restrict__ kb = k_t + (size_t)b * NPIX * DQ;

  // ---- prologue: st = S(0) ----
  f32x16 st;
  {
    const int mc0 = w * 32;
    const short8 kf0 = *(const short8*)(kb + (mc0 * 32 + l31) * DQ + hl * 8);
    const short8 kf1 = *(const short8*)(kb + (mc0 * 32 + l31) * DQ + 16 + hl * 8);
    #pragma unroll
    for (int r = 0; r < 16; ++r) st[r] = 0.f;
    st = __builtin_amdgcn_mfma_f32_32x32x16_bf16(kf0, qf[0], st, 0, 0, 0);
    st = __builtin_amdgcn_mfma_f32_32x32x16_bf16(kf1, qf[1], st, 0, 0, 0);
  }

  for (int cc = 0; cc < 32; ++cc) {
    const int mc = w * 32 + cc;

    // ---- P(cc) = exp2(st) (q pre-scaled by log2e), l partial, pack ----
    u32 pk[4][2];
    #pragma unroll
    for (int g = 0; g < 4; ++g) {
      const float e0 = fexp2(st[4 * g + 0]);
      const float e1 = fexp2(st[4 * g + 1]);
      const float e2 = fexp2(st[4 * g + 2]);
      const float e3 = fexp2(st[4 * g + 3]);
      lrun += (e0 + e1) + (e2 + e3);
      pk[g][0] = cvtpk_bf16(e0, e1);
      pk[g][1] = cvtpk_bf16(e2, e3);
    }

    // ---- st = S(cc+1): st regs free after exp; result not needed until
    //      next iter's exp -> K-load + MFMA latency hidden under PV ----
    {
      const int mcn = w * 32 + ((cc < 31) ? cc + 1 : 31);
      const short8 kf0 = *(const short8*)(kb + (mcn * 32 + l31) * DQ + hl * 8);
      const short8 kf1 = *(const short8*)(kb + (mcn * 32 + l31) * DQ + 16 + hl * 8);
      #pragma unroll
      for (int r = 0; r < 16; ++r) st[r] = 0.f;
      st = __builtin_amdgcn_mfma_f32_32x32x16_bf16(kf0, qf[0], st, 0, 0, 0);
      st = __builtin_amdgcn_mfma_f32_32x32x16_bf16(kf1, qf[1], st, 0, 0, 0);
    }

    // ---- PV(cc): acc[ct] += V^T(A) . P^T(B) per kc ----
    const size_t vbase = ((size_t)b * 128 + mc) * 8192;
    #pragma unroll
    for (int kc = 0; kc < 2; ++kc) {
      union { uint4 u; short8 s; } bu;
      half_swap(pk[2 * kc][0], pk[2 * kc][1], pk[2 * kc + 1][0], pk[2 * kc + 1][1], hl, bu.u);
      #pragma unroll
      for (int ct = 0; ct < 8; ++ct) {
        const short8 av = *(const short8*)(v_swz + vbase + (size_t)(((ct * 2 + kc) * 2 + hl) * 256) + l31 * 8);
        acc[ct] = __builtin_amdgcn_mfma_f32_32x32x16_bf16(av, bu.s, acc[ct], 0, 0, 0);
      }
    }
  }

  // ---- cross-wave additive combine (no max-sub => partials just add) ----
  lbuf[w][lane] = lrun;
  __syncthreads();
  for (int src = 1; src < 4; ++src) {
    if (w == src) {
      #pragma unroll
      for (int ct = 0; ct < 8; ++ct)
        #pragma unroll
        for (int r = 0; r < 16; ++r)
          cbuf[(ct * 16 + r) * 64 + lane] = acc[ct][r];
    }
    __syncthreads();
    if (w == 0) {
      #pragma unroll
      for (int ct = 0; ct < 8; ++ct)
        #pragma unroll
        for (int r = 0; r < 16; ++r)
          acc[ct][r] += cbuf[(ct * 16 + r) * 64 + lane];
    }
    __syncthreads();
  }

  // ---- epilogue (wave 0): out = gamma * y/l + x ----
  if (w == 0) {
    float l = (lbuf[0][lane] + lbuf[1][lane]) + (lbuf[2][lane] + lbuf[3][lane]);
    l += __shfl_xor(l, 32);                    // combine the two half-columns
    const float linv = 1.0f / l;
    const float g = gamma[0];
    #pragma unroll
    for (int ct = 0; ct < 8; ++ct)
      #pragma unroll
      for (int r = 0; r < 16; ++r) {
        const int c = ct * 32 + (r & 3) + 8 * (r >> 2) + 4 * hl;
        const size_t idx = ((size_t)b * CH + c) * NPIX + n0 + l31;
        out[idx] = g * acc[ct][r] * linv + x[idx];
      }
  }
}

// ---------------------------------------------------------------------------
extern "C" void kernel_launch(void* const* d_in, const int* in_sizes, int n_in,
                              void* d_out, int out_size, void* d_ws, size_t ws_size,
                              hipStream_t stream) {
  const float* x  = (const float*)d_in[0];
  const float* Wq = (const float*)d_in[1];
  const float* bq = (const float*)d_in[2];
  const float* Wk = (const float*)d_in[3];
  const float* bk = (const float*)d_in[4];
  const float* Wv = (const float*)d_in[5];
  const float* bv = (const float*)d_in[6];
  const float* gm = (const float*)d_in[7];
  float* out = (float*)d_out;

  // ws: q_t 1MB | k_t 1MB | v_swz 8MB (all bf16) — 10MB
  const size_t qk_elems = (size_t)BATCH * NPIX * DQ;
  const size_t v_elems  = (size_t)BATCH * NPIX * CH;
  const size_t need = (2 * qk_elems + v_elems) * sizeof(u16);
  if (ws_size < need) return;

  u16* q_t   = (u16*)d_ws;
  u16* k_t   = q_t + qk_elems;
  u16* v_swz = k_t + qk_elems;

  // xt planes live in d_out (dead until attn's epilogue overwrites it)
  u16* xt_hi = (u16*)d_out;
  u16* xt_lo = xt_hi + (size_t)BATCH * NPIX * CH;

  xprep<<<dim3(NPIX / 128, CH / 64, BATCH + 1), 256, 0, stream>>>(
      x, xt_hi, xt_lo, Wq, bq, Wk, bk, Wv, bv);
  proj<<<dim3(32 * 10 * BATCH), 256, 0, stream>>>(xt_hi, xt_lo, q_t, k_t, v_swz);
  attn<<<dim3((NPIX / 32) * BATCH), 256, 0, stream>>>(q_t, k_t, v_swz, x, gm, out);
}